// Round 11
// baseline (188.373 us; speedup 1.0000x reference)
//
#include <hip/hip_runtime.h>

// ContractExpand, compute/expand split:
//   K1 ce_y:   r10 tile structure, but stores only DISTINCT rows y[n,b,g,:]
//              as bf16 (59 MB instead of 307 MB) into d_ws.
//   K2 expand: pure grid-stride stream (no LDS/barrier/MFMA): reads y
//              (L2/L3-hot) and writes the expanded 307 MB output coalesced.
// Rationale: every {GEMM -> expanded-store} block variant pins at ~145 us
// with all pipes idle; pure streams hit 7 TB/s. Decouple the big write
// stream from the tile/barrier structure.

typedef short bf16x8 __attribute__((ext_vector_type(8)));
typedef short bf16x4 __attribute__((ext_vector_type(4)));
typedef float f32x4  __attribute__((ext_vector_type(4)));

namespace {
constexpr int D    = 300;
constexpr int LSEQ = 800;
constexpr int KP   = 320;    // padded K (10 steps of 32)
constexpr int NP   = 320;    // padded N rows of Wb
constexpr int CSTR = 308;    // cout row stride (floats)
constexpr int YSTR = 304;    // y row stride (bf16)
constexpr int SMEM_BYTES = 32 * CSTR * 4;          // 39424
constexpr size_t WB_SHORTS = (size_t)5 * NP * KP;  // 512000
// y row bases per scale (compact): G = 800,400,200,80,32 per batch of 64
constexpr int YB0 = 0, YB1 = 51200, YB2 = 76800, YB3 = 89600, YB4 = 94720;
constexpr int YROWS = 96768;
constexpr size_t WS_NEEDED = (WB_SHORTS + (size_t)YROWS * YSTR) * 2;  // ~59.9 MB
}

__device__ __forceinline__ unsigned short f2bf(float f) {
  unsigned u = __float_as_uint(f);
  u += 0x7fffu + ((u >> 16) & 1u);   // RNE
  return (unsigned short)(u >> 16);
}

// vectorized W convert: one bf16x8 per thread-item
__global__ __launch_bounds__(256)
void convert_w(const float* __restrict__ W, short* __restrict__ Wb) {
  const int item = blockIdx.x * 256 + threadIdx.x;   // 64000 items
  if (item >= 5 * NP * KP / 8) return;
  const int off = item * 8;
  const int n   = off / (NP * KP);
  const int rem = off - n * (NP * KP);
  const int c   = rem / KP;
  const int k0  = rem - c * KP;
  float s[8];
  #pragma unroll
  for (int j = 0; j < 8; ++j) s[j] = 0.f;
  if (c < D) {
    const float* wp = W + (size_t)n * D * D + (size_t)c * D + k0;
    if (k0 < 296) {
      const float4 v0 = *(const float4*)(wp);
      const float4 v1 = *(const float4*)(wp + 4);
      s[0] = v0.x; s[1] = v0.y; s[2] = v0.z; s[3] = v0.w;
      s[4] = v1.x; s[5] = v1.y; s[6] = v1.z; s[7] = v1.w;
    } else if (k0 == 296) {
      const float4 v0 = *(const float4*)(wp);
      s[0] = v0.x; s[1] = v0.y; s[2] = v0.z; s[3] = v0.w;
    }
  }
  bf16x8 p;
  #pragma unroll
  for (int j = 0; j < 8; ++j) p[j] = (short)f2bf(s[j]);
  *(bf16x8*)(Wb + (size_t)off) = p;
}

// ===================== K1: GEMM -> compact bf16 y =====================

template<int N, int R, int G, int YB>
__device__ __forceinline__ void ce_body(const int tile, char* __restrict__ smem,
    const float* __restrict__ x, const short* __restrict__ Wb,
    const float* __restrict__ bias, short* __restrict__ y) {
  const int tid = threadIdx.x;
  const int m0  = tile * 32;                 // first group-row; M_total = 64*G
  constexpr int BQ = (R <= 5) ? R : 5;       // rows per load-batch

  // ---- phase 1: seg-sums, batched loads -> bf16 swizzled LDS [32][320] ----
  #pragma unroll
  for (int it = 0; it < 5; ++it) {
    const int cidx = tid + it * 256;         // 32 rows x 40 chunks
    const int row  = cidx / 40;
    const int k0   = (cidx - row * 40) * 8;
    float s[8];
    #pragma unroll
    for (int j = 0; j < 8; ++j) s[j] = 0.f;
    if (k0 < D) {
      const int m   = m0 + row;
      const int bb  = m / G;
      const int grp = m - bb * G;
      const float* xp = x + ((size_t)(bb * LSEQ + grp * R)) * D + k0;
      if (k0 <= D - 8) {
        for (int qb = 0; qb < R; qb += BQ) {
          float4 a0[BQ], a1[BQ];
          #pragma unroll
          for (int j = 0; j < BQ; ++j) {
            a0[j] = *(const float4*)(xp + (size_t)(qb + j) * D);
            a1[j] = *(const float4*)(xp + (size_t)(qb + j) * D + 4);
          }
          #pragma unroll
          for (int j = 0; j < BQ; ++j) {
            s[0] += a0[j].x; s[1] += a0[j].y; s[2] += a0[j].z; s[3] += a0[j].w;
            s[4] += a1[j].x; s[5] += a1[j].y; s[6] += a1[j].z; s[7] += a1[j].w;
          }
        }
      } else {                               // k0 == 296: cols 296..299 only
        for (int qb = 0; qb < R; qb += BQ) {
          float4 a0[BQ];
          #pragma unroll
          for (int j = 0; j < BQ; ++j)
            a0[j] = *(const float4*)(xp + (size_t)(qb + j) * D);
          #pragma unroll
          for (int j = 0; j < BQ; ++j) {
            s[0] += a0[j].x; s[1] += a0[j].y; s[2] += a0[j].z; s[3] += a0[j].w;
          }
        }
      }
    }
    bf16x8 p;
    #pragma unroll
    for (int j = 0; j < 8; ++j) p[j] = (short)f2bf(s[j]);
    const int boff = (row * 640 + k0 * 2) ^ ((row & 7) << 4);
    *(bf16x8*)(smem + boff) = p;
  }

  // first B-frags issued before the barrier
  const int wv   = tid >> 6;
  const int lane = tid & 63;
  const int cr   = lane & 15;    // A row / B col / C col
  const int kh   = lane >> 4;    // k-half; C row = kh*4 + reg

  const short* __restrict__ Wn = Wb + (size_t)N * NP * KP;
  const short* __restrict__ wp[5];
  #pragma unroll
  for (int t = 0; t < 5; ++t)
    wp[t] = Wn + (size_t)((wv * 5 + t) * 16 + cr) * KP + kh * 8;

  bf16x8 bpre[5];
  #pragma unroll
  for (int t = 0; t < 5; ++t) bpre[t] = *(const bf16x8*)(wp[t]);

  __syncthreads();

  // ---- phase 2: MFMA, prefetched A (LDS) and B (global W) ----
  f32x4 acc[2][5];
  #pragma unroll
  for (int mt = 0; mt < 2; ++mt)
    #pragma unroll
    for (int t = 0; t < 5; ++t) acc[mt][t] = (f32x4){0.f, 0.f, 0.f, 0.f};

  const int swz0 = (cr & 7) << 4;
  const int abase0 = cr * 640        + kh * 16;
  const int abase1 = (16 + cr) * 640 + kh * 16;

  bf16x8 a0pre = *(const bf16x8*)(smem + (abase0 ^ swz0));
  bf16x8 a1pre = *(const bf16x8*)(smem + (abase1 ^ swz0));

  #pragma unroll
  for (int ks = 0; ks < 10; ++ks) {
    bf16x8 bcur[5];
    #pragma unroll
    for (int t = 0; t < 5; ++t) bcur[t] = bpre[t];
    const bf16x8 a0 = a0pre, a1 = a1pre;
    if (ks < 9) {
      #pragma unroll
      for (int t = 0; t < 5; ++t) bpre[t] = *(const bf16x8*)(wp[t] + (ks + 1) * 32);
      a0pre = *(const bf16x8*)(smem + ((abase0 + (ks + 1) * 64) ^ swz0));
      a1pre = *(const bf16x8*)(smem + ((abase1 + (ks + 1) * 64) ^ swz0));
    }
    #pragma unroll
    for (int t = 0; t < 5; ++t) {
      acc[0][t] = __builtin_amdgcn_mfma_f32_16x16x32_bf16(a0, bcur[t], acc[0][t], 0, 0, 0);
      acc[1][t] = __builtin_amdgcn_mfma_f32_16x16x32_bf16(a1, bcur[t], acc[1][t], 0, 0, 0);
    }
  }
  __syncthreads();                           // LDS reused for cout

  // ---- phase 3: bias + relu + /R -> fp32 LDS tile [32][CSTR] ----
  float* __restrict__ cout = (float*)smem;
  const float inv_r = 1.0f / (float)R;
  #pragma unroll
  for (int t = 0; t < 5; ++t) {
    const int col = (wv * 5 + t) * 16 + cr;
    if (col < D) {
      const float bv = bias[N * D + col];
      #pragma unroll
      for (int mt = 0; mt < 2; ++mt)
        #pragma unroll
        for (int j = 0; j < 4; ++j) {
          const int row = mt * 16 + kh * 4 + j;
          cout[row * CSTR + col] = fmaxf(acc[mt][t][j] + bv, 0.f) * inv_r;
        }
    }
  }
  __syncthreads();

  // ---- phase 4: compact bf16 y stores (32 rows x 75 short4 chunks) ----
  for (int i = tid; i < 32 * 75; i += 256) {
    const int ml = i / 75;
    const int c4 = i - ml * 75;
    const f32x4 v = *(const f32x4*)(cout + ml * CSTR + c4 * 4);
    bf16x4 p;
    p[0] = (short)f2bf(v[0]); p[1] = (short)f2bf(v[1]);
    p[2] = (short)f2bf(v[2]); p[3] = (short)f2bf(v[3]);
    *(bf16x4*)(y + (size_t)(YB + m0 + ml) * YSTR + c4 * 4) = p;
  }
}

__global__ __launch_bounds__(256, 4)
void ce_y(const float* __restrict__ x, const short* __restrict__ Wb,
          const float* __restrict__ bias, short* __restrict__ y) {
  __shared__ __align__(16) char smem[SMEM_BYTES];
  const int bid = blockIdx.x;                // scale-major, heavy-r first
  if (bid < 64)        ce_body<4, 25, 32 , YB4>(bid,        smem, x, Wb, bias, y);
  else if (bid < 224)  ce_body<3, 10, 80 , YB3>(bid - 64,   smem, x, Wb, bias, y);
  else if (bid < 624)  ce_body<2, 4, 200 , YB2>(bid - 224,  smem, x, Wb, bias, y);
  else if (bid < 1424) ce_body<1, 2, 400 , YB1>(bid - 624,  smem, x, Wb, bias, y);
  else                 ce_body<0, 1, 800 , YB0>(bid - 1424, smem, x, Wb, bias, y);
}

// ===================== K2: pure-stream expansion =====================

template<int N, int R, int YB>
__device__ __forceinline__ void expand_scale(const short* __restrict__ y,
    float* __restrict__ out, const int bloc, const int nblocks) {
  constexpr int ITEMS = 64 * LSEQ * 75;      // float4-chunks per scale
  for (int i = bloc * 256 + (int)threadIdx.x; i < ITEMS; i += nblocks * 256) {
    const int row = i / 75;                  // 0..51199  (b*800 + l)
    const int c4  = i - row * 75;
    const int b   = row / LSEQ;
    const int l   = row - b * LSEQ;
    const int g   = l / R;                   // compile-time divisor
    const bf16x4 sv =
        *(const bf16x4*)(y + (size_t)(YB + b * (LSEQ / R) + g) * YSTR + c4 * 4);
    f32x4 v;
    v[0] = __uint_as_float(((unsigned)(unsigned short)sv[0]) << 16);
    v[1] = __uint_as_float(((unsigned)(unsigned short)sv[1]) << 16);
    v[2] = __uint_as_float(((unsigned)(unsigned short)sv[2]) << 16);
    v[3] = __uint_as_float(((unsigned)(unsigned short)sv[3]) << 16);
    *(f32x4*)(out + ((size_t)(N * 64 + b) * LSEQ + l) * D + c4 * 4) = v;
  }
}

__global__ __launch_bounds__(256)
void expand(const short* __restrict__ y, float* __restrict__ out) {
  constexpr int BPS = 410;                   // blocks per scale
  const int s    = blockIdx.x / BPS;
  const int bloc = blockIdx.x - s * BPS;
  if (s == 0)      expand_scale<0, 1 , YB0>(y, out, bloc, BPS);
  else if (s == 1) expand_scale<1, 2 , YB1>(y, out, bloc, BPS);
  else if (s == 2) expand_scale<2, 4 , YB2>(y, out, bloc, BPS);
  else if (s == 3) expand_scale<3, 10, YB3>(y, out, bloc, BPS);
  else             expand_scale<4, 25, YB4>(y, out, bloc, BPS);
}

// ===================== Fallback (r10 fused, needs only Wb) =====================

template<int N, int R, int G>
__device__ __forceinline__ void ce_body_fb(const int tile, char* __restrict__ smem,
    const float* __restrict__ x, const short* __restrict__ Wb,
    const float* __restrict__ bias, float* __restrict__ out) {
  const int tid = threadIdx.x;
  const int m0  = tile * 32;
  constexpr int BQ = (R <= 5) ? R : 5;
  #pragma unroll
  for (int it = 0; it < 5; ++it) {
    const int cidx = tid + it * 256;
    const int row  = cidx / 40;
    const int k0   = (cidx - row * 40) * 8;
    float s[8];
    #pragma unroll
    for (int j = 0; j < 8; ++j) s[j] = 0.f;
    if (k0 < D) {
      const int m   = m0 + row;
      const int bb  = m / G;
      const int grp = m - bb * G;
      const float* xp = x + ((size_t)(bb * LSEQ + grp * R)) * D + k0;
      if (k0 <= D - 8) {
        for (int qb = 0; qb < R; qb += BQ) {
          float4 a0[BQ], a1[BQ];
          #pragma unroll
          for (int j = 0; j < BQ; ++j) {
            a0[j] = *(const float4*)(xp + (size_t)(qb + j) * D);
            a1[j] = *(const float4*)(xp + (size_t)(qb + j) * D + 4);
          }
          #pragma unroll
          for (int j = 0; j < BQ; ++j) {
            s[0] += a0[j].x; s[1] += a0[j].y; s[2] += a0[j].z; s[3] += a0[j].w;
            s[4] += a1[j].x; s[5] += a1[j].y; s[6] += a1[j].z; s[7] += a1[j].w;
          }
        }
      } else {
        for (int qb = 0; qb < R; qb += BQ) {
          float4 a0[BQ];
          #pragma unroll
          for (int j = 0; j < BQ; ++j)
            a0[j] = *(const float4*)(xp + (size_t)(qb + j) * D);
          #pragma unroll
          for (int j = 0; j < BQ; ++j) {
            s[0] += a0[j].x; s[1] += a0[j].y; s[2] += a0[j].z; s[3] += a0[j].w;
          }
        }
      }
    }
    bf16x8 p;
    #pragma unroll
    for (int j = 0; j < 8; ++j) p[j] = (short)f2bf(s[j]);
    const int boff = (row * 640 + k0 * 2) ^ ((row & 7) << 4);
    *(bf16x8*)(smem + boff) = p;
  }
  const int wv   = tid >> 6;
  const int lane = tid & 63;
  const int cr   = lane & 15;
  const int kh   = lane >> 4;
  const short* __restrict__ Wn = Wb + (size_t)N * NP * KP;
  const short* __restrict__ wp[5];
  #pragma unroll
  for (int t = 0; t < 5; ++t)
    wp[t] = Wn + (size_t)((wv * 5 + t) * 16 + cr) * KP + kh * 8;
  bf16x8 bpre[5];
  #pragma unroll
  for (int t = 0; t < 5; ++t) bpre[t] = *(const bf16x8*)(wp[t]);
  __syncthreads();
  f32x4 acc[2][5];
  #pragma unroll
  for (int mt = 0; mt < 2; ++mt)
    #pragma unroll
    for (int t = 0; t < 5; ++t) acc[mt][t] = (f32x4){0.f, 0.f, 0.f, 0.f};
  const int swz0 = (cr & 7) << 4;
  const int abase0 = cr * 640        + kh * 16;
  const int abase1 = (16 + cr) * 640 + kh * 16;
  bf16x8 a0pre = *(const bf16x8*)(smem + (abase0 ^ swz0));
  bf16x8 a1pre = *(const bf16x8*)(smem + (abase1 ^ swz0));
  #pragma unroll
  for (int ks = 0; ks < 10; ++ks) {
    bf16x8 bcur[5];
    #pragma unroll
    for (int t = 0; t < 5; ++t) bcur[t] = bpre[t];
    const bf16x8 a0 = a0pre, a1 = a1pre;
    if (ks < 9) {
      #pragma unroll
      for (int t = 0; t < 5; ++t) bpre[t] = *(const bf16x8*)(wp[t] + (ks + 1) * 32);
      a0pre = *(const bf16x8*)(smem + ((abase0 + (ks + 1) * 64) ^ swz0));
      a1pre = *(const bf16x8*)(smem + ((abase1 + (ks + 1) * 64) ^ swz0));
    }
    #pragma unroll
    for (int t = 0; t < 5; ++t) {
      acc[0][t] = __builtin_amdgcn_mfma_f32_16x16x32_bf16(a0, bcur[t], acc[0][t], 0, 0, 0);
      acc[1][t] = __builtin_amdgcn_mfma_f32_16x16x32_bf16(a1, bcur[t], acc[1][t], 0, 0, 0);
    }
  }
  __syncthreads();
  float* __restrict__ cout = (float*)smem;
  const float inv_r = 1.0f / (float)R;
  #pragma unroll
  for (int t = 0; t < 5; ++t) {
    const int col = (wv * 5 + t) * 16 + cr;
    if (col < D) {
      const float bv = bias[N * D + col];
      #pragma unroll
      for (int mt = 0; mt < 2; ++mt)
        #pragma unroll
        for (int j = 0; j < 4; ++j) {
          const int row = mt * 16 + kh * 4 + j;
          cout[row * CSTR + col] = fmaxf(acc[mt][t][j] + bv, 0.f) * inv_r;
        }
    }
  }
  __syncthreads();
  constexpr int TOTAL = 32 * R * 75;
  for (int i = tid; i < TOTAL; i += 256) {
    const int rowrep = i / 75;
    const int chunk  = i - rowrep * 75;
    const int ml     = rowrep / R;
    const int q      = rowrep - ml * R;
    const int m      = m0 + ml;
    const int bb     = m / G;
    const int grp    = m - bb * G;
    const f32x4 v = *(const f32x4*)(cout + ml * CSTR + chunk * 4);
    float* __restrict__ op =
        out + ((size_t)((N * 64 + bb) * LSEQ) + grp * R + q) * D + chunk * 4;
    *(f32x4*)op = v;
  }
}

__global__ __launch_bounds__(256, 4)
void ce_mfma_fb(const float* __restrict__ x, const short* __restrict__ Wb,
                const float* __restrict__ bias, float* __restrict__ out) {
  __shared__ __align__(16) char smem[SMEM_BYTES];
  const int bid = blockIdx.x;
  if (bid < 64)        ce_body_fb<4, 25, 32 >(bid,        smem, x, Wb, bias, out);
  else if (bid < 224)  ce_body_fb<3, 10, 80 >(bid - 64,   smem, x, Wb, bias, out);
  else if (bid < 624)  ce_body_fb<2, 4, 200 >(bid - 224,  smem, x, Wb, bias, out);
  else if (bid < 1424) ce_body_fb<1, 2, 400 >(bid - 624,  smem, x, Wb, bias, out);
  else                 ce_body_fb<0, 1, 800 >(bid - 1424, smem, x, Wb, bias, out);
}

extern "C" void kernel_launch(void* const* d_in, const int* in_sizes, int n_in,
                              void* d_out, int out_size, void* d_ws, size_t ws_size,
                              hipStream_t stream) {
  const float* x    = (const float*)d_in[0];  // [64, 800, 300]
  const float* W    = (const float*)d_in[1];  // [5, 300, 300]
  const float* bias = (const float*)d_in[2];  // [5, 300]
  float* out        = (float*)d_out;          // [5, 64, 800, 300]
  short* ws         = (short*)d_ws;

  convert_w<<<250, 256, 0, stream>>>(W, ws);
  if (ws_size >= WS_NEEDED) {
    short* y = ws + WB_SHORTS;
    ce_y<<<3024, 256, 0, stream>>>(x, ws, bias, y);
    expand<<<2050, 256, 0, stream>>>(y, out);
  } else {
    ce_mfma_fb<<<3024, 256, 0, stream>>>(x, ws, bias, out);
  }
}